// Round 6
// baseline (300.137 us; speedup 1.0000x reference)
//
#include <hip/hip_runtime.h>
#include <stdint.h>

#define N_NODES 50000
#define E_EDGES 300000
#define C_CH    256
#define H_HEADS 8
#define NB_SORT 256      // blocks in counting sort
#define CHUNK   1172     // edges per sort block (256*1172 >= 300000)
#define MB_KV   782      // ceil(50000/64) m-blocks for K/V

typedef unsigned short u16;
typedef unsigned int   u32;

typedef __attribute__((ext_vector_type(8))) short  v8s;   // 8 bf16 (MFMA A/B frag)
typedef __attribute__((ext_vector_type(4))) float  v4f;   // MFMA C/D frag

__device__ __forceinline__ float bf2f(u16 v) {
    union { u32 u; float f; } x; x.u = ((u32)v) << 16; return x.f;
}
__device__ __forceinline__ u16 f2bf(float f) {
    union { float f; u32 u; } x; x.f = f;
    u32 r = (x.u + 0x7FFFu + ((x.u >> 16) & 1u)) >> 16;
    return (u16)r;
}
__device__ __forceinline__ u32 pack2(float a, float b) {
    return (u32)f2bf(a) | ((u32)f2bf(b) << 16);
}
__device__ __forceinline__ void unp2(u32 v, float& lo, float& hi) {
    union { u32 u; float f; } x;
    x.u = v << 16; lo = x.f;
    x.u = v & 0xFFFF0000u; hi = x.f;
}

// ---------------------------------------------------------------------------
// Unified GEMM: per block one 64x256 output tile of K, V (blocks 0..1563,
// K/V pair for same m adjacent in dispatch -> X tile L2/LLC-shared) or Q
// (blocks 1564..1567). A staged fp32->bf16 per k-slice (64 rows x 32 k);
// B staged fp32->bf16 full-N (256 rows x FULL 32 k — round-5 bug was 16).
// mfma_f32_16x16x32_bf16, fp32 acc.
// ---------------------------------------------------------------------------
#define LDB 40   // LDS row stride in bf16 elems (80 B: 16B-aligned, 2-way max)

__global__ __launch_bounds__(256) void gemm_all(
    const float* __restrict__ X,
    const float* __restrict__ Wq, const float* __restrict__ Wk,
    const float* __restrict__ Wv,
    const float* __restrict__ bq, const float* __restrict__ bk,
    const float* __restrict__ bv,
    u16* __restrict__ Qb, u16* __restrict__ Kb, u16* __restrict__ Vb)
{
    __shared__ u16 As[64 * LDB];    //  5.0 KB
    __shared__ u16 Bs[256 * LDB];   // 20.5 KB
    const int b = blockIdx.x;
    const float* W; const float* bias; u16* OUT; int m0, M;
    if (b < 2 * MB_KV) {
        int sel = b & 1;
        W = sel ? Wv : Wk; bias = sel ? bv : bk; OUT = sel ? Vb : Kb;
        m0 = (b >> 1) * 64; M = N_NODES;
    } else {
        W = Wq; bias = bq; OUT = Qb; m0 = (b - 2 * MB_KV) * 64; M = 256;
    }
    const int t = threadIdx.x;
    const int lane = t & 63, wave = t >> 6;
    const int quad = lane >> 4, l15 = lane & 15;

    v4f acc[16];
#pragma unroll
    for (int i = 0; i < 16; i++) acc[i] = (v4f)(0.0f);

    const int ar = t >> 2, as8 = (t & 3) * 8;   // A-stage: row, 8-float seg

    for (int k0 = 0; k0 < 256; k0 += 32) {
        // --- stage A: 64 rows x 32 k, fp32 -> bf16 ---
        int gr = m0 + ar;
        float4 f0 = make_float4(0.f,0.f,0.f,0.f), f1 = f0;
        if (gr < M) {
            const float* xp = X + (size_t)gr * 256 + k0 + as8;
            f0 = *(const float4*)xp; f1 = *(const float4*)(xp + 4);
        }
        uint4 ap;
        ap.x = pack2(f0.x, f0.y); ap.y = pack2(f0.z, f0.w);
        ap.z = pack2(f1.x, f1.y); ap.w = pack2(f1.z, f1.w);
        *(uint4*)(As + ar * LDB + as8) = ap;
        // --- stage B: one full row (32 k) per thread, fp32 -> bf16 ---
        const float* wp = W + (size_t)t * 256 + k0;
        float4 g0 = *(const float4*)(wp),      g1 = *(const float4*)(wp + 4);
        float4 g2 = *(const float4*)(wp + 8),  g3 = *(const float4*)(wp + 12);
        float4 g4 = *(const float4*)(wp + 16), g5 = *(const float4*)(wp + 20);
        float4 g6 = *(const float4*)(wp + 24), g7 = *(const float4*)(wp + 28);
        uint4 bp0, bp1, bp2, bp3;
        bp0.x = pack2(g0.x, g0.y); bp0.y = pack2(g0.z, g0.w);
        bp0.z = pack2(g1.x, g1.y); bp0.w = pack2(g1.z, g1.w);
        bp1.x = pack2(g2.x, g2.y); bp1.y = pack2(g2.z, g2.w);
        bp1.z = pack2(g3.x, g3.y); bp1.w = pack2(g3.z, g3.w);
        bp2.x = pack2(g4.x, g4.y); bp2.y = pack2(g4.z, g4.w);
        bp2.z = pack2(g5.x, g5.y); bp2.w = pack2(g5.z, g5.w);
        bp3.x = pack2(g6.x, g6.y); bp3.y = pack2(g6.z, g6.w);
        bp3.z = pack2(g7.x, g7.y); bp3.w = pack2(g7.z, g7.w);
        *(uint4*)(Bs + t * LDB)      = bp0;
        *(uint4*)(Bs + t * LDB + 8)  = bp1;
        *(uint4*)(Bs + t * LDB + 16) = bp2;
        *(uint4*)(Bs + t * LDB + 24) = bp3;
        __syncthreads();

        v8s a = *(const v8s*)(As + (wave * 16 + l15) * LDB + quad * 8);
#pragma unroll
        for (int nt = 0; nt < 16; nt++) {
            v8s bb = *(const v8s*)(Bs + (nt * 16 + l15) * LDB + quad * 8);
            acc[nt] = __builtin_amdgcn_mfma_f32_16x16x32_bf16(a, bb, acc[nt], 0, 0, 0);
        }
        __syncthreads();
    }

#pragma unroll
    for (int nt = 0; nt < 16; nt++) {
        int n = nt * 16 + l15;
        float bi = bias[n];
#pragma unroll
        for (int r = 0; r < 4; r++) {
            int m = m0 + wave * 16 + quad * 4 + r;   // C/D: row=quad*4+reg, col=lane&15
            if (m < M) OUT[(size_t)m * 256 + n] = f2bf(acc[nt][r] + bi);
        }
    }
}

// ---------------------------------------------------------------------------
// Counting sort pass 1: per-block LDS histogram of dst -> blockhist[b][256].
// Also builds the anchor adjacency bitmask (rare atomicOr, ~1.5k edges).
// ---------------------------------------------------------------------------
__global__ __launch_bounds__(256) void hist_k(
    const int* __restrict__ src, const int* __restrict__ dst,
    u32* __restrict__ blockhist, u32* __restrict__ inmask)
{
    __shared__ u32 hist[256];
    int t = threadIdx.x, b = blockIdx.x;
    hist[t] = 0;
    __syncthreads();
    int start = b * CHUNK;
    int end = start + CHUNK; if (end > E_EDGES) end = E_EDGES;
    for (int e = start + t; e < end; e += 256) {
        int d = dst[e];
        atomicAdd(&hist[d], 1u);            // LDS atomic: cheap
        int s = src[e];
        if (s < 256) atomicOr(&inmask[d * 8 + (s >> 5)], 1u << (s & 31));
    }
    __syncthreads();
    blockhist[b * 256 + t] = hist[t];
}

// ---------------------------------------------------------------------------
// Counting sort pass 2 (1 block): dst totals, exclusive scan -> dst_off[257],
// per-(block,dst) base offsets -> blockbase[b][d]. Deterministic, no atomics.
// ---------------------------------------------------------------------------
__global__ __launch_bounds__(256) void off_k(
    const u32* __restrict__ blockhist, u32* __restrict__ dst_off,
    u32* __restrict__ blockbase)
{
    __shared__ u32 tmp[256];
    int d = threadIdx.x;
    u32 tot = 0;
    for (int b = 0; b < NB_SORT; b++) tot += blockhist[b * 256 + d];
    tmp[d] = tot;
    __syncthreads();
    for (int off = 1; off < 256; off <<= 1) {
        u32 add = (d >= off) ? tmp[d - off] : 0u;
        __syncthreads();
        tmp[d] += add;
        __syncthreads();
    }
    u32 excl = tmp[d] - tot;
    dst_off[d] = excl;
    if (d == 255) dst_off[256] = tmp[255];
    u32 base = excl;
    for (int b = 0; b < NB_SORT; b++) {
        blockbase[b * 256 + d] = base;
        base += blockhist[b * 256 + d];
    }
}

// ---------------------------------------------------------------------------
// Counting sort pass 3: scatter edge ids using LDS cursors (no global atomics).
// ---------------------------------------------------------------------------
__global__ __launch_bounds__(256) void scatter2_k(
    const int* __restrict__ dst, const u32* __restrict__ blockbase,
    u32* __restrict__ eidx)
{
    __shared__ u32 cur[256];
    int t = threadIdx.x, b = blockIdx.x;
    cur[t] = blockbase[b * 256 + t];
    __syncthreads();
    int start = b * CHUNK;
    int end = start + CHUNK; if (end > E_EDGES) end = E_EDGES;
    for (int e = start + t; e < end; e += 256) {
        u32 pos = atomicAdd(&cur[dst[e]], 1u);   // LDS atomic
        eidx[pos] = (u32)e;
    }
}

// ---------------------------------------------------------------------------
// SPD: 3-level exact-length reachability on the 256-anchor subgraph.
// T[i*256+m] = first k in {1,2,3} with walk of length k from m to i, else 4.
// spd[e] = T[src][dst] for src<256, else 4.  One block.
// ---------------------------------------------------------------------------
__global__ __launch_bounds__(256) void spd_levels(
    const u32* __restrict__ inmask, unsigned char* __restrict__ T)
{
    __shared__ u32 F1[256][8], F2[256][8], F3[256][8];
    int i = threadIdx.x;
#pragma unroll
    for (int w = 0; w < 8; w++) { F1[i][w] = inmask[i * 8 + w]; F2[i][w] = 0; F3[i][w] = 0; }
    __syncthreads();
    for (int w = 0; w < 8; w++) {
        u32 m = F1[i][w];
        while (m) {
            int b = __ffs(m) - 1; m &= m - 1;
            int s = w * 32 + b;
#pragma unroll
            for (int j = 0; j < 8; j++) F2[i][j] |= F1[s][j];
        }
    }
    __syncthreads();
    for (int w = 0; w < 8; w++) {
        u32 m = F1[i][w];
        while (m) {
            int b = __ffs(m) - 1; m &= m - 1;
            int s = w * 32 + b;
#pragma unroll
            for (int j = 0; j < 8; j++) F3[i][j] |= F2[s][j];
        }
    }
    __syncthreads();
    for (int w = 0; w < 8; w++) {
        u32 f1 = F1[i][w], f2 = F2[i][w], f3 = F3[i][w];
#pragma unroll
        for (int g = 0; g < 8; g++) {
            u32 word = 0;
#pragma unroll
            for (int b = 0; b < 4; b++) {
                int bit = g * 4 + b;
                u32 k = ((f1 >> bit) & 1u) ? 1u : ((f2 >> bit) & 1u) ? 2u
                       : ((f3 >> bit) & 1u) ? 3u : 4u;
                word |= k << (8 * b);
            }
            *(u32*)(T + i * 256 + w * 32 + g * 4) = word;
        }
    }
}

// ---------------------------------------------------------------------------
// Fused scores+aggregate: blockIdx = d*8 + part. Lane layout: 2 edges per
// wave (half = lane>>5), 32 lanes x 8 channels each (uint4 = 16 B loads).
// Q[d] loaded once (block-invariant). Per edge: K dot (4-lane shuffle),
// spd bias, exp, V FMA into 8 fp32 acc. Halves merged via shfl_xor 32.
// ---------------------------------------------------------------------------
__global__ __launch_bounds__(256) void agg_k(
    const int* __restrict__ src, const u32* __restrict__ eidx,
    const u32* __restrict__ dst_off, const u16* __restrict__ Qb,
    const u16* __restrict__ Kb, const u16* __restrict__ Vb,
    const unsigned char* __restrict__ T, const float* __restrict__ spd_w,
    float* __restrict__ out, float* __restrict__ denom)
{
    __shared__ float red[4 * 256];
    __shared__ float dred[4 * 8];
    int d    = blockIdx.x >> 3;
    int part = blockIdx.x & 7;
    int t = threadIdx.x, lane = t & 63, wave = t >> 6;
    int half = lane >> 5, sl = lane & 31;
    int h = sl >> 2;                        // head = (sl*8)>>5
    u32 start = dst_off[d], end = dst_off[d + 1];

    uint4 qv = *(const uint4*)(Qb + (size_t)d * 256 + sl * 8);
    float q0,q1,q2,q3,q4,q5,q6,q7;
    unp2(qv.x,q0,q1); unp2(qv.y,q2,q3); unp2(qv.z,q4,q5); unp2(qv.w,q6,q7);
    float sw4 = spd_w[4 * 8 + h];           // spd=4 bias (src>=256, ~98.5% of edges)

    float a0=0.f,a1=0.f,a2=0.f,a3=0.f,a4=0.f,a5=0.f,a6=0.f,a7=0.f,dsum=0.f;
    for (u32 i = start + (u32)(part * 8 + wave * 2 + half); i < end; i += 64) {
        u32 e = eidx[i];                    // 2 distinct edges per wave
        int s = src[e];
        uint4 kv = *(const uint4*)(Kb + (size_t)s * 256 + sl * 8);
        uint4 vv = *(const uint4*)(Vb + (size_t)s * 256 + sl * 8);
        float k0,k1,k2,k3,k4,k5,k6,k7, v0,v1,v2,v3,v4,v5,v6,v7;
        unp2(kv.x,k0,k1); unp2(kv.y,k2,k3); unp2(kv.z,k4,k5); unp2(kv.w,k6,k7);
        unp2(vv.x,v0,v1); unp2(vv.y,v2,v3); unp2(vv.z,v4,v5); unp2(vv.w,v6,v7);
        float p = q0*k0+q1*k1+q2*k2+q3*k3+q4*k4+q5*k5+q6*k6+q7*k7;
        p += __shfl_xor(p, 1);
        p += __shfl_xor(p, 2);              // head dot over 4 lanes x 8 ch
        float bias = (s < 256) ? spd_w[(int)T[s * 256 + d] * 8 + h] : sw4;
        float w = __expf(p * 0.17677669529663689f + bias);
        a0 += w*v0; a1 += w*v1; a2 += w*v2; a3 += w*v3;
        a4 += w*v4; a5 += w*v5; a6 += w*v6; a7 += w*v7;
        if ((sl & 3) == 0) dsum += w;
    }
    a0 += __shfl_xor(a0,32); a1 += __shfl_xor(a1,32);
    a2 += __shfl_xor(a2,32); a3 += __shfl_xor(a3,32);
    a4 += __shfl_xor(a4,32); a5 += __shfl_xor(a5,32);
    a6 += __shfl_xor(a6,32); a7 += __shfl_xor(a7,32);
    dsum += __shfl_xor(dsum,32);
    if (half == 0) {
        *(float4*)(&red[wave * 256 + sl * 8])     = make_float4(a0,a1,a2,a3);
        *(float4*)(&red[wave * 256 + sl * 8 + 4]) = make_float4(a4,a5,a6,a7);
        if ((sl & 3) == 0) dred[wave * 8 + h] = dsum;
    }
    __syncthreads();
    float sAll = red[t] + red[256 + t] + red[512 + t] + red[768 + t];
    atomicAdd(&out[(size_t)d * 256 + t], sAll);
    if (t < 8) {
        float ds = dred[t] + dred[8 + t] + dred[16 + t] + dred[24 + t];
        atomicAdd(&denom[d * 8 + t], ds);
    }
}

// ---------------------------------------------------------------------------
// LayerNorm: h = out/denom (anchors only) + x.  deg is constant per row ->
// cancels exactly under LN; skipped.  One wave per node, fp32 in/out.
// ---------------------------------------------------------------------------
__global__ __launch_bounds__(256) void ln_k(
    const float* __restrict__ x, const float* __restrict__ out,
    const float* __restrict__ denom, const float* __restrict__ gamma,
    const float* __restrict__ beta, float* __restrict__ y)
{
    int n = blockIdx.x * 4 + (threadIdx.x >> 6);
    if (n >= N_NODES) return;
    int lane = threadIdx.x & 63;
    int ch = lane * 4;
    float4 xv = *(const float4*)(x + (size_t)n * 256 + ch);
    float h0 = xv.x, h1 = xv.y, h2 = xv.z, h3 = xv.w;
    if (n < 256) {
        float den = denom[n * 8 + (lane >> 3)];
        float inv = (den > 0.f) ? 1.0f / den : 0.0f;
        const float* op = out + (size_t)n * 256 + ch;
        h0 += op[0] * inv; h1 += op[1] * inv;
        h2 += op[2] * inv; h3 += op[3] * inv;
    }
    float s = h0 + h1 + h2 + h3;
#pragma unroll
    for (int off = 1; off < 64; off <<= 1) s += __shfl_xor(s, off);
    float mu = s * (1.0f / 256.0f);
    float d0 = h0 - mu, d1 = h1 - mu, d2 = h2 - mu, d3 = h3 - mu;
    float q = d0 * d0 + d1 * d1 + d2 * d2 + d3 * d3;
#pragma unroll
    for (int off = 1; off < 64; off <<= 1) q += __shfl_xor(q, off);
    float rstd = rsqrtf(q * (1.0f / 256.0f) + 1e-5f);
    float4 gv = *(const float4*)(gamma + ch);
    float4 bv = *(const float4*)(beta + ch);
    float4 o;
    o.x = d0 * rstd * gv.x + bv.x;
    o.y = d1 * rstd * gv.y + bv.y;
    o.z = d2 * rstd * gv.z + bv.z;
    o.w = d3 * rstd * gv.w + bv.w;
    *(float4*)(y + (size_t)n * 256 + ch) = o;
}

// ---------------------------------------------------------------------------
extern "C" void kernel_launch(void* const* d_in, const int* in_sizes, int n_in,
                              void* d_out, int out_size, void* d_ws, size_t ws_size,
                              hipStream_t stream)
{
    const float* x     = (const float*)d_in[0];
    const int*   src   = (const int*)d_in[1];
    const int*   dst   = (const int*)d_in[2];
    const float* Wq    = (const float*)d_in[3];
    const float* bq    = (const float*)d_in[4];
    const float* Wk    = (const float*)d_in[5];
    const float* bk    = (const float*)d_in[6];
    const float* Wv    = (const float*)d_in[7];
    const float* bv    = (const float*)d_in[8];
    const float* spd_w = (const float*)d_in[9];
    const float* gamma = (const float*)d_in[10];
    const float* beta  = (const float*)d_in[11];
    float* y = (float*)d_out;

    char* ws = (char*)d_ws;
    // --- zeroed region [0, 278528) ---
    float* denom     = (float*)(ws + 0);          //   8192 B
    float* outf      = (float*)(ws + 8192);       // 262144 B
    u32*   inmask    = (u32*)(ws + 270336);       //   8192 B (zero region ends 278528)
    // --- rest (all written before read) ---
    u32*   dst_off   = (u32*)(ws + 278528);       //   1028 B (pad to 280576)
    unsigned char* T = (unsigned char*)(ws + 280576); // 65536 B
    u32*   blockhist = (u32*)(ws + 346112);       // 262144 B
    u32*   blockbase = (u32*)(ws + 608256);       // 262144 B
    u32*   eidx      = (u32*)(ws + 870400);       // 1.2 MB
    u16*   Qb        = (u16*)(ws + 2070400);      // 128 KB
    u16*   Kb        = (u16*)(ws + 2201472);      // 25.6 MB
    u16*   Vb        = (u16*)(ws + 27801472);     // 25.6 MB (end ~53.4 MB)

    hipMemsetAsync(d_ws, 0, 278528, stream);

    dim3 blk(256);
    gemm_all<<<dim3(2 * MB_KV + 4), blk, 0, stream>>>(
        x, Wq, Wk, Wv, bq, bk, bv, Qb, Kb, Vb);
    hist_k<<<dim3(NB_SORT), blk, 0, stream>>>(src, dst, blockhist, inmask);
    off_k<<<dim3(1), blk, 0, stream>>>(blockhist, dst_off, blockbase);
    spd_levels<<<dim3(1), blk, 0, stream>>>(inmask, T);
    scatter2_k<<<dim3(NB_SORT), blk, 0, stream>>>(dst, blockbase, eidx);
    agg_k<<<dim3(256 * 8), blk, 0, stream>>>(src, eidx, dst_off, Qb, Kb, Vb, T, spd_w, outf, denom);
    ln_k<<<dim3((N_NODES + 3) / 4), blk, 0, stream>>>(x, outf, denom, gamma, beta, y);
}

// Round 8
// 268.543 us; speedup vs baseline: 1.1177x; 1.1177x over previous
//
#include <hip/hip_runtime.h>
#include <stdint.h>

#define N_NODES 50000
#define E_EDGES 300000
#define C_CH    256
#define H_HEADS 8
#define NB_SORT 256      // blocks in counting sort
#define CHUNK   1172     // edges per sort block (256*1172 >= 300000)

typedef unsigned short u16;
typedef unsigned int   u32;

typedef __attribute__((ext_vector_type(8))) short  v8s;   // 8 bf16 (MFMA A/B frag)
typedef __attribute__((ext_vector_type(4))) float  v4f;   // MFMA C/D frag

__device__ __forceinline__ float bf2f(u16 v) {
    union { u32 u; float f; } x; x.u = ((u32)v) << 16; return x.f;
}
__device__ __forceinline__ u16 f2bf(float f) {
    union { float f; u32 u; } x; x.f = f;
    u32 r = (x.u + 0x7FFFu + ((x.u >> 16) & 1u)) >> 16;
    return (u16)r;
}
__device__ __forceinline__ void unp2(u32 v, float& lo, float& hi) {
    union { u32 u; float f; } x;
    x.u = v << 16; lo = x.f;
    x.u = v & 0xFFFF0000u; hi = x.f;
}
// async global->LDS, 16 B/lane; LDS dest = wave-uniform base + lane*16
__device__ __forceinline__ void gl_lds16(const u16* g, u16* l) {
    __builtin_amdgcn_global_load_lds(
        (const __attribute__((address_space(1))) void*)g,
        (__attribute__((address_space(3))) void*)l, 16, 0, 0);
}

// ---------------------------------------------------------------------------
// Convert X[50000,256] and Wk,Wv,Wq -> bf16 (Wb packed K,V,Q). One launch.
// ---------------------------------------------------------------------------
__global__ __launch_bounds__(256) void cvt_all(
    const float* __restrict__ x, const float* __restrict__ Wk,
    const float* __restrict__ Wv, const float* __restrict__ Wq,
    u16* __restrict__ Xb, u16* __restrict__ Wb)
{
    int b = blockIdx.x;
    const float* src; u16* dst; int off;
    if (b < 12500) { src = x; dst = Xb; off = b * 1024; }
    else {
        int wb = b - 12500;               // 0..191, 64 blocks per matrix
        int m = (wb < 64) ? 0 : (wb < 128) ? 1 : 2;
        src = (m == 0) ? Wk : (m == 1) ? Wv : Wq;
        dst = Wb + m * 65536; off = (wb & 63) * 1024;
    }
    int i = off + threadIdx.x * 4;
    float4 v = *(const float4*)(src + i);
    ushort4 o;
    o.x = f2bf(v.x); o.y = f2bf(v.y); o.z = f2bf(v.z); o.w = f2bf(v.w);
    *(ushort4*)(dst + i) = o;
}

// ---------------------------------------------------------------------------
// m97-style bf16 GEMM: OUT[*,256] = Xb @ W^T + bias. 128x128 tile, BK=64,
// global_load_lds width-16 staging: 4 insts per wave per matrix per k-tile
// (4 waves x 4 x 1024 B = 16 KB tile — round-7 bug was 1 inst = 1/4 tile).
// 4 waves x 4x4 16x16x32 frags. grid=(6,391): x = mat*2+nhalf (K,V,Q).
// ---------------------------------------------------------------------------
__global__ __launch_bounds__(256) void gemm3(
    const u16* __restrict__ Xb, const u16* __restrict__ Wb,
    const float* __restrict__ bk, const float* __restrict__ bv,
    const float* __restrict__ bq,
    u16* __restrict__ Kb, u16* __restrict__ Vb, u16* __restrict__ Qb)
{
    __shared__ u16 As[128 * 64];   // 16 KB, row-major, NO pad (global_load_lds)
    __shared__ u16 Bs[128 * 64];   // 16 KB
    const int mat = blockIdx.x >> 1, nh = blockIdx.x & 1;
    const int m0 = blockIdx.y * 128;
    if (mat == 2 && m0 >= 256) return;           // Q: only first 2 m-tiles
    const int M = (mat == 2) ? 256 : N_NODES;
    const u16* W = Wb + mat * 65536;
    const float* bias = (mat == 0) ? bk : (mat == 1) ? bv : bq;
    u16* OUT = (mat == 0) ? Kb : (mat == 1) ? Vb : Qb;
    const int n0 = nh * 128;

    const int t = threadIdx.x, lane = t & 63, w = t >> 6;
    const int quad = lane >> 4, l15 = lane & 15;
    const int mq = w & 1, nq = w >> 1;

    v4f acc[16];
#pragma unroll
    for (int i = 0; i < 16; i++) acc[i] = (v4f)(0.0f);

    // staging: wave w covers rows w*32..w*32+31 in 4 chunks of 8 rows.
    // chunk j: lane -> row w*32+j*8+lane/8, cols (lane&7)*8..+7  (16 B)
    const int lrow = lane >> 3;          // 0..7
    const int scol = (lane & 7) * 8;
    const u16* gA = Xb + (size_t)(m0 + w * 32 + lrow) * 256 + scol;
    const u16* gB = W  + (size_t)(n0 + w * 32 + lrow) * 256 + scol;

    for (int kt = 0; kt < 256; kt += 64) {
#pragma unroll
        for (int j = 0; j < 4; j++) {
            gl_lds16(gA + (size_t)j * 8 * 256 + kt, As + (w * 32 + j * 8) * 64);
            gl_lds16(gB + (size_t)j * 8 * 256 + kt, Bs + (w * 32 + j * 8) * 64);
        }
        __syncthreads();                  // compiler drains vmcnt before barrier
#pragma unroll
        for (int ks = 0; ks < 2; ks++) {
            v8s a[4], b[4];
#pragma unroll
            for (int f = 0; f < 4; f++)
                a[f] = *(const v8s*)(As + (mq * 64 + f * 16 + l15) * 64 + ks * 32 + quad * 8);
#pragma unroll
            for (int f = 0; f < 4; f++)
                b[f] = *(const v8s*)(Bs + (nq * 64 + f * 16 + l15) * 64 + ks * 32 + quad * 8);
#pragma unroll
            for (int fm = 0; fm < 4; fm++)
#pragma unroll
                for (int fn = 0; fn < 4; fn++)
                    acc[fm * 4 + fn] = __builtin_amdgcn_mfma_f32_16x16x32_bf16(
                        a[fm], b[fn], acc[fm * 4 + fn], 0, 0, 0);
        }
        __syncthreads();
    }

#pragma unroll
    for (int fn = 0; fn < 4; fn++) {
        int n = n0 + nq * 64 + fn * 16 + l15;
        float bi = bias[n];
#pragma unroll
        for (int fm = 0; fm < 4; fm++) {
#pragma unroll
            for (int r = 0; r < 4; r++) {
                int m = m0 + mq * 64 + fm * 16 + quad * 4 + r;  // row=quad*4+r, col=l15
                if (m < M) OUT[(size_t)m * 256 + n] = f2bf(acc[fm * 4 + fn][r] + bi);
            }
        }
    }
}

// ---------------------------------------------------------------------------
// Counting sort pass 1: per-block LDS histogram of dst -> blockhist[b][256].
// Also builds the anchor adjacency bitmask (rare atomicOr, ~1.5k edges).
// ---------------------------------------------------------------------------
__global__ __launch_bounds__(256) void hist_k(
    const int* __restrict__ src, const int* __restrict__ dst,
    u32* __restrict__ blockhist, u32* __restrict__ inmask)
{
    __shared__ u32 hist[256];
    int t = threadIdx.x, b = blockIdx.x;
    hist[t] = 0;
    __syncthreads();
    int start = b * CHUNK;
    int end = start + CHUNK; if (end > E_EDGES) end = E_EDGES;
    for (int e = start + t; e < end; e += 256) {
        int d = dst[e];
        atomicAdd(&hist[d], 1u);            // LDS atomic: cheap
        int s = src[e];
        if (s < 256) atomicOr(&inmask[d * 8 + (s >> 5)], 1u << (s & 31));
    }
    __syncthreads();
    blockhist[b * 256 + t] = hist[t];
}

// ---------------------------------------------------------------------------
// Counting sort pass 2 (1 block): dst totals, exclusive scan -> dst_off[257],
// per-(block,dst) base offsets -> blockbase[b][d]. Deterministic, no atomics.
// ---------------------------------------------------------------------------
__global__ __launch_bounds__(256) void off_k(
    const u32* __restrict__ blockhist, u32* __restrict__ dst_off,
    u32* __restrict__ blockbase)
{
    __shared__ u32 tmp[256];
    int d = threadIdx.x;
    u32 tot = 0;
    for (int b = 0; b < NB_SORT; b++) tot += blockhist[b * 256 + d];
    tmp[d] = tot;
    __syncthreads();
    for (int off = 1; off < 256; off <<= 1) {
        u32 add = (d >= off) ? tmp[d - off] : 0u;
        __syncthreads();
        tmp[d] += add;
        __syncthreads();
    }
    u32 excl = tmp[d] - tot;
    dst_off[d] = excl;
    if (d == 255) dst_off[256] = tmp[255];
    u32 base = excl;
    for (int b = 0; b < NB_SORT; b++) {
        blockbase[b * 256 + d] = base;
        base += blockhist[b * 256 + d];
    }
}

// ---------------------------------------------------------------------------
// Counting sort pass 3: scatter edge ids using LDS cursors (no global atomics).
// ---------------------------------------------------------------------------
__global__ __launch_bounds__(256) void scatter2_k(
    const int* __restrict__ dst, const u32* __restrict__ blockbase,
    u32* __restrict__ eidx)
{
    __shared__ u32 cur[256];
    int t = threadIdx.x, b = blockIdx.x;
    cur[t] = blockbase[b * 256 + t];
    __syncthreads();
    int start = b * CHUNK;
    int end = start + CHUNK; if (end > E_EDGES) end = E_EDGES;
    for (int e = start + t; e < end; e += 256) {
        u32 pos = atomicAdd(&cur[dst[e]], 1u);   // LDS atomic
        eidx[pos] = (u32)e;
    }
}

// ---------------------------------------------------------------------------
// SPD: 3-level exact-length reachability on the 256-anchor subgraph.
// T[i*256+m] = first k in {1,2,3} with walk of length k from m to i, else 4.
// spd[e] = T[src][dst] for src<256, else 4.  One block.
// ---------------------------------------------------------------------------
__global__ __launch_bounds__(256) void spd_levels(
    const u32* __restrict__ inmask, unsigned char* __restrict__ T)
{
    __shared__ u32 F1[256][8], F2[256][8], F3[256][8];
    int i = threadIdx.x;
#pragma unroll
    for (int w = 0; w < 8; w++) { F1[i][w] = inmask[i * 8 + w]; F2[i][w] = 0; F3[i][w] = 0; }
    __syncthreads();
    for (int w = 0; w < 8; w++) {
        u32 m = F1[i][w];
        while (m) {
            int b = __ffs(m) - 1; m &= m - 1;
            int s = w * 32 + b;
#pragma unroll
            for (int j = 0; j < 8; j++) F2[i][j] |= F1[s][j];
        }
    }
    __syncthreads();
    for (int w = 0; w < 8; w++) {
        u32 m = F1[i][w];
        while (m) {
            int b = __ffs(m) - 1; m &= m - 1;
            int s = w * 32 + b;
#pragma unroll
            for (int j = 0; j < 8; j++) F3[i][j] |= F2[s][j];
        }
    }
    __syncthreads();
    for (int w = 0; w < 8; w++) {
        u32 f1 = F1[i][w], f2 = F2[i][w], f3 = F3[i][w];
#pragma unroll
        for (int g = 0; g < 8; g++) {
            u32 word = 0;
#pragma unroll
            for (int b = 0; b < 4; b++) {
                int bit = g * 4 + b;
                u32 k = ((f1 >> bit) & 1u) ? 1u : ((f2 >> bit) & 1u) ? 2u
                       : ((f3 >> bit) & 1u) ? 3u : 4u;
                word |= k << (8 * b);
            }
            *(u32*)(T + i * 256 + w * 32 + g * 4) = word;
        }
    }
}

// ---------------------------------------------------------------------------
// Fused scores+aggregate: blockIdx = d*8 + part. Lane layout: 2 edges per
// wave (half = lane>>5), 32 lanes x 8 channels each (uint4 = 16 B loads).
// Q[d] loaded once (block-invariant). Per edge: K dot (4-lane shuffle),
// spd bias, exp, V FMA into 8 fp32 acc. Halves merged via shfl_xor 32.
// ---------------------------------------------------------------------------
__global__ __launch_bounds__(256) void agg_k(
    const int* __restrict__ src, const u32* __restrict__ eidx,
    const u32* __restrict__ dst_off, const u16* __restrict__ Qb,
    const u16* __restrict__ Kb, const u16* __restrict__ Vb,
    const unsigned char* __restrict__ T, const float* __restrict__ spd_w,
    float* __restrict__ out, float* __restrict__ denom)
{
    __shared__ float red[4 * 256];
    __shared__ float dred[4 * 8];
    int d    = blockIdx.x >> 3;
    int part = blockIdx.x & 7;
    int t = threadIdx.x, lane = t & 63, wave = t >> 6;
    int half = lane >> 5, sl = lane & 31;
    int h = sl >> 2;                        // head = (sl*8)>>5
    u32 start = dst_off[d], end = dst_off[d + 1];

    uint4 qv = *(const uint4*)(Qb + (size_t)d * 256 + sl * 8);
    float q0,q1,q2,q3,q4,q5,q6,q7;
    unp2(qv.x,q0,q1); unp2(qv.y,q2,q3); unp2(qv.z,q4,q5); unp2(qv.w,q6,q7);
    float sw4 = spd_w[4 * 8 + h];           // spd=4 bias (src>=256, ~98.5% of edges)

    float a0=0.f,a1=0.f,a2=0.f,a3=0.f,a4=0.f,a5=0.f,a6=0.f,a7=0.f,dsum=0.f;
    for (u32 i = start + (u32)(part * 8 + wave * 2 + half); i < end; i += 64) {
        u32 e = eidx[i];                    // 2 distinct edges per wave
        int s = src[e];
        uint4 kv = *(const uint4*)(Kb + (size_t)s * 256 + sl * 8);
        uint4 vv = *(const uint4*)(Vb + (size_t)s * 256 + sl * 8);
        float k0,k1,k2,k3,k4,k5,k6,k7, v0,v1,v2,v3,v4,v5,v6,v7;
        unp2(kv.x,k0,k1); unp2(kv.y,k2,k3); unp2(kv.z,k4,k5); unp2(kv.w,k6,k7);
        unp2(vv.x,v0,v1); unp2(vv.y,v2,v3); unp2(vv.z,v4,v5); unp2(vv.w,v6,v7);
        float p = q0*k0+q1*k1+q2*k2+q3*k3+q4*k4+q5*k5+q6*k6+q7*k7;
        p += __shfl_xor(p, 1);
        p += __shfl_xor(p, 2);              // head dot over 4 lanes x 8 ch
        float bias = (s < 256) ? spd_w[(int)T[s * 256 + d] * 8 + h] : sw4;
        float w = __expf(p * 0.17677669529663689f + bias);
        a0 += w*v0; a1 += w*v1; a2 += w*v2; a3 += w*v3;
        a4 += w*v4; a5 += w*v5; a6 += w*v6; a7 += w*v7;
        if ((sl & 3) == 0) dsum += w;
    }
    a0 += __shfl_xor(a0,32); a1 += __shfl_xor(a1,32);
    a2 += __shfl_xor(a2,32); a3 += __shfl_xor(a3,32);
    a4 += __shfl_xor(a4,32); a5 += __shfl_xor(a5,32);
    a6 += __shfl_xor(a6,32); a7 += __shfl_xor(a7,32);
    dsum += __shfl_xor(dsum,32);
    if (half == 0) {
        *(float4*)(&red[wave * 256 + sl * 8])     = make_float4(a0,a1,a2,a3);
        *(float4*)(&red[wave * 256 + sl * 8 + 4]) = make_float4(a4,a5,a6,a7);
        if ((sl & 3) == 0) dred[wave * 8 + h] = dsum;
    }
    __syncthreads();
    float sAll = red[t] + red[256 + t] + red[512 + t] + red[768 + t];
    atomicAdd(&out[(size_t)d * 256 + t], sAll);
    if (t < 8) {
        float ds = dred[t] + dred[8 + t] + dred[16 + t] + dred[24 + t];
        atomicAdd(&denom[d * 8 + t], ds);
    }
}

// ---------------------------------------------------------------------------
// LayerNorm: h = out/denom (anchors only) + x.  deg is constant per row ->
// cancels exactly under LN; skipped.  One wave per node, fp32 in/out.
// ---------------------------------------------------------------------------
__global__ __launch_bounds__(256) void ln_k(
    const float* __restrict__ x, const float* __restrict__ out,
    const float* __restrict__ denom, const float* __restrict__ gamma,
    const float* __restrict__ beta, float* __restrict__ y)
{
    int n = blockIdx.x * 4 + (threadIdx.x >> 6);
    if (n >= N_NODES) return;
    int lane = threadIdx.x & 63;
    int ch = lane * 4;
    float4 xv = *(const float4*)(x + (size_t)n * 256 + ch);
    float h0 = xv.x, h1 = xv.y, h2 = xv.z, h3 = xv.w;
    if (n < 256) {
        float den = denom[n * 8 + (lane >> 3)];
        float inv = (den > 0.f) ? 1.0f / den : 0.0f;
        const float* op = out + (size_t)n * 256 + ch;
        h0 += op[0] * inv; h1 += op[1] * inv;
        h2 += op[2] * inv; h3 += op[3] * inv;
    }
    float s = h0 + h1 + h2 + h3;
#pragma unroll
    for (int off = 1; off < 64; off <<= 1) s += __shfl_xor(s, off);
    float mu = s * (1.0f / 256.0f);
    float d0 = h0 - mu, d1 = h1 - mu, d2 = h2 - mu, d3 = h3 - mu;
    float q = d0 * d0 + d1 * d1 + d2 * d2 + d3 * d3;
#pragma unroll
    for (int off = 1; off < 64; off <<= 1) q += __shfl_xor(q, off);
    float rstd = rsqrtf(q * (1.0f / 256.0f) + 1e-5f);
    float4 gv = *(const float4*)(gamma + ch);
    float4 bv = *(const float4*)(beta + ch);
    float4 o;
    o.x = d0 * rstd * gv.x + bv.x;
    o.y = d1 * rstd * gv.y + bv.y;
    o.z = d2 * rstd * gv.z + bv.z;
    o.w = d3 * rstd * gv.w + bv.w;
    *(float4*)(y + (size_t)n * 256 + ch) = o;
}

// ---------------------------------------------------------------------------
extern "C" void kernel_launch(void* const* d_in, const int* in_sizes, int n_in,
                              void* d_out, int out_size, void* d_ws, size_t ws_size,
                              hipStream_t stream)
{
    const float* x     = (const float*)d_in[0];
    const int*   src   = (const int*)d_in[1];
    const int*   dst   = (const int*)d_in[2];
    const float* Wq    = (const float*)d_in[3];
    const float* bq    = (const float*)d_in[4];
    const float* Wk    = (const float*)d_in[5];
    const float* bk    = (const float*)d_in[6];
    const float* Wv    = (const float*)d_in[7];
    const float* bv    = (const float*)d_in[8];
    const float* spd_w = (const float*)d_in[9];
    const float* gamma = (const float*)d_in[10];
    const float* beta  = (const float*)d_in[11];
    float* y = (float*)d_out;

    char* ws = (char*)d_ws;
    // --- zeroed region [0, 278528) ---
    float* denom     = (float*)(ws + 0);          //   8192 B
    float* outf      = (float*)(ws + 8192);       // 262144 B
    u32*   inmask    = (u32*)(ws + 270336);       //   8192 B (zero region ends 278528)
    // --- rest (all written before read) ---
    u32*   dst_off   = (u32*)(ws + 278528);       //   1028 B (pad to 280576)
    unsigned char* T = (unsigned char*)(ws + 280576); // 65536 B
    u32*   blockhist = (u32*)(ws + 346112);       // 262144 B
    u32*   blockbase = (u32*)(ws + 608256);       // 262144 B
    u32*   eidx      = (u32*)(ws + 870400);       // 1.2 MB
    u16*   Qb        = (u16*)(ws + 2070400);      // 128 KB
    u16*   Kb        = (u16*)(ws + 2201472);      // 25.6 MB
    u16*   Vb        = (u16*)(ws + 27801472);     // 25.6 MB
    u16*   Xb        = (u16*)(ws + 53401472);     // 50176*512 B = 25.69 MB (pad rows read-only)
    u16*   Wb        = (u16*)(ws + 79091584);     // 3*65536*2 = 384 KB (end ~79.5 MB)

    hipMemsetAsync(d_ws, 0, 278528, stream);

    dim3 blk(256);
    cvt_all<<<dim3(12692), blk, 0, stream>>>(x, Wk, Wv, Wq, Xb, Wb);
    gemm3<<<dim3(6, 391), blk, 0, stream>>>(Xb, Wb, bk, bv, bq, Kb, Vb, Qb);
    hist_k<<<dim3(NB_SORT), blk, 0, stream>>>(src, dst, blockhist, inmask);
    off_k<<<dim3(1), blk, 0, stream>>>(blockhist, dst_off, blockbase);
    spd_levels<<<dim3(1), blk, 0, stream>>>(inmask, T);
    scatter2_k<<<dim3(NB_SORT), blk, 0, stream>>>(dst, blockbase, eidx);
    agg_k<<<dim3(256 * 8), blk, 0, stream>>>(src, eidx, dst_off, Qb, Kb, Vb, T, spd_w, outf, denom);
    ln_k<<<dim3((N_NODES + 3) / 4), blk, 0, stream>>>(x, outf, denom, gamma, beta, y);
}